// Round 1
// baseline (776.370 us; speedup 1.0000x reference)
//
#include <hip/hip_runtime.h>

// Problem constants (reference: tokens=8192, hidden=7168, experts=256)
#define HIDDEN  7168
#define EXPERTS 256
#define TOPK    8
#define NGROUP  8
#define TOPKGRP 4
#define GRPSZ   (EXPERTS / NGROUP)   // 32
#define SCALE   2.5f

// ---------------- GEMM + sigmoid + bias ----------------
// C[t,e] = sigmoid(sum_h A[t,h]*B[h,e]) + bias[e]
// Tile 64x64, BK=32, 256 threads, 4x4 per thread.
#define BM 64
#define BN 64
#define BK 32
#define APAD 68   // padded row stride for transposed A tile (16B-aligned rows, low write conflict)

__global__ __launch_bounds__(256) void gemm_sigmoid_bias(
    const float* __restrict__ A,    // [T, HIDDEN]
    const float* __restrict__ B,    // [HIDDEN, EXPERTS]
    const float* __restrict__ bias, // [EXPERTS]
    float* __restrict__ S)          // [T, EXPERTS]
{
    __shared__ __align__(16) float As[BK][APAD]; // As[k][m] = A[t0+m][k0+k]
    __shared__ __align__(16) float Bs[BK][BN];   // Bs[k][n] = B[k0+k][e0+n]

    const int tid = threadIdx.x;
    const int tx  = tid & 15;   // expert sub-tile
    const int ty  = tid >> 4;   // token sub-tile
    const int t0  = blockIdx.y * BM;
    const int e0  = blockIdx.x * BN;

    float acc[4][4] = {};

    for (int k0 = 0; k0 < HIDDEN; k0 += BK) {
        // Stage A tile (64 rows x 32 k) transposed into LDS
#pragma unroll
        for (int j = 0; j < 8; ++j) {
            int i = tid + 256 * j;
            int r = i >> 5;       // token row 0..63
            int c = i & 31;       // k col 0..31
            As[c][r] = A[(size_t)(t0 + r) * HIDDEN + k0 + c];
        }
        // Stage B tile (32 k x 64 experts)
#pragma unroll
        for (int j = 0; j < 8; ++j) {
            int i = tid + 256 * j;
            int r = i >> 6;       // k row 0..31
            int c = i & 63;       // expert col 0..63
            Bs[r][c] = B[(size_t)(k0 + r) * EXPERTS + e0 + c];
        }
        __syncthreads();

#pragma unroll
        for (int kk = 0; kk < BK; ++kk) {
            float4 a4 = *(const float4*)&As[kk][ty * 4];
            float4 b4 = *(const float4*)&Bs[kk][tx * 4];
            float a[4] = {a4.x, a4.y, a4.z, a4.w};
            float b[4] = {b4.x, b4.y, b4.z, b4.w};
#pragma unroll
            for (int i2 = 0; i2 < 4; ++i2)
#pragma unroll
                for (int j2 = 0; j2 < 4; ++j2)
                    acc[i2][j2] = fmaf(a[i2], b[j2], acc[i2][j2]);
        }
        __syncthreads();
    }

    // Epilogue: sigmoid + bias, store scores_for_choice
#pragma unroll
    for (int i2 = 0; i2 < 4; ++i2) {
        int t = t0 + ty * 4 + i2;
#pragma unroll
        for (int j2 = 0; j2 < 4; ++j2) {
            int e = e0 + tx * 4 + j2;
            float x  = acc[i2][j2];
            float sc = 1.0f / (1.0f + __expf(-x)) + bias[e];
            S[(size_t)t * EXPERTS + e] = sc;
        }
    }
}

// ---------------- Group-limited top-k routing ----------------
// One thread per token. Matches reference semantics:
//  - group score = sum of top-2 scores_for_choice within each group of 32
//  - select top-4 groups (first-index wins ties, like jax.lax.top_k)
//  - top-8 over masked scores where masked entries are 0.0 (list init to 0
//    exactly models the >=8 masked zeros present in the reference's array)
//  - renormalize by (sum + 1e-20), scale by 2.5
__global__ __launch_bounds__(256) void route_topk(
    const float* __restrict__ S,  // [T, EXPERTS]
    float* __restrict__ out,      // [T, TOPK]
    int T)
{
    int t = blockIdx.x * blockDim.x + threadIdx.x;
    if (t >= T) return;

    const float4* s4 = (const float4*)(S + (size_t)t * EXPERTS);

    // Pass 1: per-group top-2 sums
    float gsum[NGROUP];
#pragma unroll
    for (int g = 0; g < NGROUP; ++g) {
        float m1 = -1e30f, m2 = -1e30f;
#pragma unroll
        for (int q = 0; q < GRPSZ / 4; ++q) {
            float4 v = s4[g * (GRPSZ / 4) + q];
            float vv[4] = {v.x, v.y, v.z, v.w};
#pragma unroll
            for (int u = 0; u < 4; ++u) {
                float x = vv[u];
                if (x > m1)      { m2 = m1; m1 = x; }
                else if (x > m2) { m2 = x; }
            }
        }
        gsum[g] = m1 + m2;
    }

    // Pass 2: top-4 groups (strict >, first index wins ties)
    unsigned selmask = 0;
#pragma unroll
    for (int r = 0; r < TOPKGRP; ++r) {
        float best = -1e30f;
        int bi = 0;
#pragma unroll
        for (int g = 0; g < NGROUP; ++g) {
            bool taken = (selmask >> g) & 1u;
            if (!taken && gsum[g] > best) { best = gsum[g]; bi = g; }
        }
        selmask |= 1u << bi;
    }

    // Pass 3: top-8 over selected groups' scores (sorted desc, init 0)
    float w[TOPK];
#pragma unroll
    for (int k = 0; k < TOPK; ++k) w[k] = 0.0f;

    for (int g = 0; g < NGROUP; ++g) {
        if (!((selmask >> g) & 1u)) continue;
#pragma unroll
        for (int q = 0; q < GRPSZ / 4; ++q) {
            float4 v = s4[g * (GRPSZ / 4) + q];
            float vv[4] = {v.x, v.y, v.z, v.w};
#pragma unroll
            for (int u = 0; u < 4; ++u) {
                float x = vv[u];
                if (x > w[TOPK - 1]) {
                    // branchless sorted insert (drops smallest)
#pragma unroll
                    for (int k = 0; k < TOPK; ++k) {
                        float hi = fmaxf(w[k], x);
                        x = fminf(w[k], x);
                        w[k] = hi;
                    }
                }
            }
        }
    }

    // Pass 4: renormalize and write
    float d = 1e-20f;
#pragma unroll
    for (int k = 0; k < TOPK; ++k) d += w[k];
    float inv = SCALE / d;

    float4 o0 = {w[0] * inv, w[1] * inv, w[2] * inv, w[3] * inv};
    float4 o1 = {w[4] * inv, w[5] * inv, w[6] * inv, w[7] * inv};
    float4* o = (float4*)(out + (size_t)t * TOPK);
    o[0] = o0;
    o[1] = o1;
}

extern "C" void kernel_launch(void* const* d_in, const int* in_sizes, int n_in,
                              void* d_out, int out_size, void* d_ws, size_t ws_size,
                              hipStream_t stream) {
    const float* A    = (const float*)d_in[0];   // hidden_states [T, HIDDEN]
    const float* B    = (const float*)d_in[1];   // kernel [HIDDEN, EXPERTS]
    const float* bias = (const float*)d_in[2];   // e_score_correction_bias [EXPERTS]
    float* out = (float*)d_out;                  // [T, TOPK]
    float* scores = (float*)d_ws;                // [T, EXPERTS] scratch (8 MB)

    const int T = in_sizes[0] / HIDDEN;          // 8192

    dim3 grid1(EXPERTS / BN, T / BM);            // (4, 128)
    gemm_sigmoid_bias<<<grid1, 256, 0, stream>>>(A, B, bias, scores);

    int nb = (T + 255) / 256;
    route_topk<<<nb, 256, 0, stream>>>(scores, out, T);
}

// Round 2
// 368.263 us; speedup vs baseline: 2.1082x; 2.1082x over previous
//
#include <hip/hip_runtime.h>
#include <stdint.h>

// Problem constants
#define T_TOK   8192
#define HID     7168
#define EXPERTS 256
#define TOPK    8
#define NGROUP  8
#define TOPKGRP 4
#define SCALE   2.5f

// GEMM config
#define KSPLIT  8
#define KCHUNK  (HID / KSPLIT)      // 896
#define BM      128
#define BN      256                 // full expert dim: A loaded exactly once
#define BK      32
#define NITER   (KCHUNK / BK)       // 28

#define AS1 __attribute__((address_space(1)))
#define AS3 __attribute__((address_space(3)))

typedef __bf16 bf16x8 __attribute__((ext_vector_type(8)));
typedef float  f32x16 __attribute__((ext_vector_type(16)));

__device__ __forceinline__ uint32_t asu(float f){ union{float f;uint32_t u;}v; v.f=f; return v.u; }
__device__ __forceinline__ float asf(uint32_t u){ union{uint32_t u;float f;}v; v.u=u; return v.f; }

// ---------------------------------------------------------------------------
// pack_b: B [HID][EXPERTS] fp32 -> Bp in MFMA-fragment order, bf16 hi/lo.
// Region (s, nt, prec): 64 lanes x 16B; lane l holds
//   bf16(B[s*16 + (l>>5)*8 + j][nt*32 + (l&31)]), j=0..7
// Flat layout: offset_bytes = ((s*8 + nt)*2 + prec)*1024 + lane*16
// => a BK=32 k-slab (2 consecutive s) is a contiguous 32 KB chunk.
// ---------------------------------------------------------------------------
__global__ __launch_bounds__(256) void pack_b(const float* __restrict__ B,
                                              uint32_t* __restrict__ Bp)
{
    int i    = blockIdx.x * 256 + threadIdx.x;   // 0 .. 448*8*64-1
    int lane = i & 63;
    int u    = i >> 6;                            // unit = s*8 + nt
    int s    = u >> 3;
    int nt   = u & 7;
    int n    = nt * 32 + (lane & 31);
    int kb   = s * 16 + (lane >> 5) * 8;

    uint32_t h[4], l[4];
#pragma unroll
    for (int w = 0; w < 4; ++w) {
        float x0 = B[(size_t)(kb + 2*w    ) * EXPERTS + n];
        float x1 = B[(size_t)(kb + 2*w + 1) * EXPERTS + n];
        uint32_t u0 = asu(x0), u1 = asu(x1);
        h[w] = (u0 >> 16) | (u1 & 0xffff0000u);
        float r0 = x0 - asf(u0 & 0xffff0000u);
        float r1 = x1 - asf(u1 & 0xffff0000u);
        l[w] = (asu(r0) >> 16) | (asu(r1) & 0xffff0000u);
    }
    uint32_t base = u * 512 + lane * 4;           // in uint32 units; hi region
    *(uint4*)(Bp + base)       = make_uint4(h[0], h[1], h[2], h[3]);
    *(uint4*)(Bp + base + 256) = make_uint4(l[0], l[1], l[2], l[3]);
}

// ---------------------------------------------------------------------------
// Split-bf16 MFMA GEMM: logits[t][e] = sum_k A[t][k]*B[k][e]
// A = hi + lo (bit-truncation split); C ~= Ah*Bh + Ah*Bl + Al*Bh.
// Block 128x256, 4 waves, wave tile 64x128, 32x32x16 bf16 MFMA.
// K-split across blockIdx.x; ATOMIC ? atomicAdd into S : write partial P[kp].
// ---------------------------------------------------------------------------
template<bool ATOMIC>
__global__ __launch_bounds__(256, 2) void gemm_bf16split(
    const float* __restrict__ A, const uint32_t* __restrict__ Bp,
    float* __restrict__ Out)
{
    // A LDS: [s2(2)][mt(4)][prec(2)][64 lanes x 16B] = 16 KB (fragment order)
    // B LDS: [s2(2)][nt(8)][prec(2)][64 lanes x 16B] = 32 KB (raw copy of Bp slab)
    __shared__ __align__(16) uint32_t As_[4096];
    __shared__ __align__(16) uint32_t Bs_[8192];

    const int tid  = threadIdx.x;
    const int lane = tid & 63;
    const int wv   = tid >> 6;            // 0..3
    const int wm   = wv >> 1;             // wave m-half
    const int wn   = wv & 1;              // wave n-half
    const int kp   = blockIdx.x;
    const int t0   = blockIdx.y * BM;
    const int k0   = kp * KCHUNK;

    // Precompute A staging: per j, idx = tid + 256j -> m = idx>>3, k4 = idx&7
    const float* aptr[4];
    uint32_t awoff[4];
#pragma unroll
    for (int j = 0; j < 4; ++j) {
        int idx = tid + 256 * j;
        int m = idx >> 3, k4 = idx & 7, k = k4 * 4;
        aptr[j] = A + (size_t)(t0 + m) * HID + k0 + k;
        int s2 = k >> 4, jh = (k >> 3) & 1, off = (k & 7) * 2;
        int mt = m >> 5;
        int wl = (m & 31) + (jh << 5);
        awoff[j] = (uint32_t)(((s2 * 4 + mt) * 2) * 1024 + wl * 16 + off);
    }
    const uint32_t* bptr = Bp + (size_t)(k0 >> 4) * 4096;  // 16 KB per s-step

    f32x16 acc[2][4];
#pragma unroll
    for (int mi = 0; mi < 2; ++mi)
#pragma unroll
        for (int ni = 0; ni < 4; ++ni)
#pragma unroll
            for (int r = 0; r < 16; ++r) acc[mi][ni][r] = 0.f;

    for (int it = 0; it < NITER; ++it) {
        __syncthreads();
        // A global loads (latency first)
        float4 av[4];
#pragma unroll
        for (int j = 0; j < 4; ++j) av[j] = *(const float4*)aptr[j];
        // B: async DMA of the contiguous 32 KB fragment-ordered slab
#pragma unroll
        for (int j = 0; j < 8; ++j) {
            int c = tid + 256 * j;
            __builtin_amdgcn_global_load_lds((const AS1 uint32_t*)(bptr + c * 4),
                                             (AS3 uint32_t*)(&Bs_[c * 4]), 16, 0, 0);
        }
        // A convert (truncation split) + fragment-ordered LDS writes
#pragma unroll
        for (int j = 0; j < 4; ++j) {
            uint32_t x0 = asu(av[j].x), x1 = asu(av[j].y);
            uint32_t x2 = asu(av[j].z), x3 = asu(av[j].w);
            uint32_t h01 = (x0 >> 16) | (x1 & 0xffff0000u);
            uint32_t h23 = (x2 >> 16) | (x3 & 0xffff0000u);
            float r0 = av[j].x - asf(x0 & 0xffff0000u);
            float r1 = av[j].y - asf(x1 & 0xffff0000u);
            float r2 = av[j].z - asf(x2 & 0xffff0000u);
            float r3 = av[j].w - asf(x3 & 0xffff0000u);
            uint32_t l01 = (asu(r0) >> 16) | (asu(r1) & 0xffff0000u);
            uint32_t l23 = (asu(r2) >> 16) | (asu(r3) & 0xffff0000u);
            char* p = (char*)As_ + awoff[j];
            *(uint2*)p          = make_uint2(h01, h23);
            *(uint2*)(p + 1024) = make_uint2(l01, l23);
        }
#pragma unroll
        for (int j = 0; j < 4; ++j) aptr[j] += BK;
        bptr += 8192;
        __syncthreads();

        // Compute: 2 k16-steps, 12 ds_read_b128 + 24 MFMA each
#pragma unroll
        for (int s2 = 0; s2 < 2; ++s2) {
            uint4 ahv[2][2], bhv[4][2];
#pragma unroll
            for (int mi = 0; mi < 2; ++mi) {
                const char* p = (char*)As_ + ((s2 * 4 + wm * 2 + mi) * 2) * 1024 + lane * 16;
                ahv[mi][0] = *(const uint4*)p;
                ahv[mi][1] = *(const uint4*)(p + 1024);
            }
#pragma unroll
            for (int ni = 0; ni < 4; ++ni) {
                const char* p = (char*)Bs_ + ((s2 * 8 + wn * 4 + ni) * 2) * 1024 + lane * 16;
                bhv[ni][0] = *(const uint4*)p;
                bhv[ni][1] = *(const uint4*)(p + 1024);
            }
#pragma unroll
            for (int mi = 0; mi < 2; ++mi) {
                bf16x8 ah = __builtin_bit_cast(bf16x8, ahv[mi][0]);
                bf16x8 al = __builtin_bit_cast(bf16x8, ahv[mi][1]);
#pragma unroll
                for (int ni = 0; ni < 4; ++ni) {
                    bf16x8 bh = __builtin_bit_cast(bf16x8, bhv[ni][0]);
                    bf16x8 bl = __builtin_bit_cast(bf16x8, bhv[ni][1]);
                    acc[mi][ni] = __builtin_amdgcn_mfma_f32_32x32x16_bf16(ah, bh, acc[mi][ni], 0, 0, 0);
                    acc[mi][ni] = __builtin_amdgcn_mfma_f32_32x32x16_bf16(ah, bl, acc[mi][ni], 0, 0, 0);
                    acc[mi][ni] = __builtin_amdgcn_mfma_f32_32x32x16_bf16(al, bh, acc[mi][ni], 0, 0, 0);
                }
            }
        }
    }

    // Epilogue: C/D layout 32x32: col=lane&31, row=(r&3)+8*(r>>2)+4*(lane>>5)
    const int col   = lane & 31;
    const int rbase = 4 * (lane >> 5);
#pragma unroll
    for (int mi = 0; mi < 2; ++mi) {
#pragma unroll
        for (int ni = 0; ni < 4; ++ni) {
#pragma unroll
            for (int r = 0; r < 16; ++r) {
                int row = (r & 3) + 8 * (r >> 2) + rbase;
                int m = t0 + wm * 64 + mi * 32 + row;
                int e = wn * 128 + ni * 32 + col;
                float v = acc[mi][ni][r];
                if (ATOMIC) atomicAdd(&Out[(size_t)m * EXPERTS + e], v);
                else        Out[(size_t)kp * T_TOK * EXPERTS + (size_t)m * EXPERTS + e] = v;
            }
        }
    }
}

// ---------------------------------------------------------------------------
// route_wave: one wave per token. Reads raw logits (sums nparts partials),
// applies sigmoid + bias, then group-limited top-k identical to reference.
// Lane l owns experts l*4..l*4+3 (group = l>>3, 8 lanes per group of 32).
// ---------------------------------------------------------------------------
__global__ __launch_bounds__(256) void route_wave(
    const float* __restrict__ P, int nparts,
    const float* __restrict__ bias, float* __restrict__ out)
{
    const int lane = threadIdx.x & 63;
    const int wv   = threadIdx.x >> 6;
    const int t    = blockIdx.x * 4 + wv;

    float4 a = {0.f, 0.f, 0.f, 0.f};
    const float* p0 = P + (size_t)t * EXPERTS + lane * 4;
    for (int p = 0; p < nparts; ++p) {
        float4 v = *(const float4*)(p0 + (size_t)p * T_TOK * EXPERTS);
        a.x += v.x; a.y += v.y; a.z += v.z; a.w += v.w;
    }
    float4 b4 = *(const float4*)(bias + lane * 4);
    float sc0 = 1.f / (1.f + __expf(-a.x)) + b4.x;
    float sc1 = 1.f / (1.f + __expf(-a.y)) + b4.y;
    float sc2 = 1.f / (1.f + __expf(-a.z)) + b4.z;
    float sc3 = 1.f / (1.f + __expf(-a.w)) + b4.w;

    // per-lane top-2 of its 4 scores
    float m1 = fmaxf(sc0, sc1), m2 = fminf(sc0, sc1);
    float tmn = fminf(m1, sc2); m1 = fmaxf(m1, sc2); m2 = fmaxf(m2, tmn);
    tmn = fminf(m1, sc3); m1 = fmaxf(m1, sc3); m2 = fmaxf(m2, tmn);

    // combine top-2 across the 8 lanes of the group (xor 1,2,4)
#pragma unroll
    for (int off = 1; off < 8; off <<= 1) {
        float om1 = __shfl_xor(m1, off);
        float om2 = __shfl_xor(m2, off);
        float mn  = fminf(m1, om1);
        m1 = fmaxf(m1, om1);
        m2 = fmaxf(mn, fmaxf(m2, om2));
    }
    float gsum = m1 + m2;

    // broadcast all 8 group sums to every lane
    float gs[8];
#pragma unroll
    for (int g = 0; g < 8; ++g) gs[g] = __shfl(gsum, g * 8);

    // top-4 groups, strict > with first-index tiebreak (matches lax.top_k)
    unsigned selmask = 0;
#pragma unroll
    for (int r = 0; r < TOPKGRP; ++r) {
        float best = -1e30f; int bi = 0;
#pragma unroll
        for (int g = 0; g < 8; ++g) {
            bool taken = (selmask >> g) & 1u;
            if (!taken && gs[g] > best) { best = gs[g]; bi = g; }
        }
        selmask |= 1u << bi;
    }
    bool keep = (selmask >> (lane >> 3)) & 1u;
    // masked scores: non-selected groups contribute 0.0 (exactly like reference)
    float v0 = keep ? sc0 : 0.f;
    float v1 = keep ? sc1 : 0.f;
    float v2 = keep ? sc2 : 0.f;
    float v3 = keep ? sc3 : 0.f;

    // 8x wave-wide max-extract
    float w[8];
    float wsum = 0.f;
#pragma unroll
    for (int itk = 0; itk < 8; ++itk) {
        float lm = fmaxf(fmaxf(v0, v1), fmaxf(v2, v3));
        float wm = lm;
#pragma unroll
        for (int off = 32; off >= 1; off >>= 1) wm = fmaxf(wm, __shfl_xor(wm, off));
        unsigned long long msk = __ballot(lm == wm);
        int first = __ffsll(msk) - 1;
        bool cl = (lane == first);
        bool c0 = cl && (v0 == wm); v0 = c0 ? -1e30f : v0; cl = cl && !c0;
        bool c1 = cl && (v1 == wm); v1 = c1 ? -1e30f : v1; cl = cl && !c1;
        bool c2 = cl && (v2 == wm); v2 = c2 ? -1e30f : v2; cl = cl && !c2;
        bool c3 = cl && (v3 == wm); v3 = c3 ? -1e30f : v3;
        w[itk] = wm;
        wsum += wm;
    }
    float inv = SCALE / (wsum + 1e-20f);
    if (lane == 0) {
        float4 o0 = {w[0] * inv, w[1] * inv, w[2] * inv, w[3] * inv};
        float4 o1 = {w[4] * inv, w[5] * inv, w[6] * inv, w[7] * inv};
        float4* op = (float4*)(out + (size_t)t * TOPK);
        op[0] = o0; op[1] = o1;
    }
}

// ---------------------------------------------------------------------------
// Legacy fp32 fallback (known-correct R1 kernels) for tiny ws_size.
// ---------------------------------------------------------------------------
__global__ __launch_bounds__(256) void gemm_sigmoid_bias(
    const float* __restrict__ A, const float* __restrict__ B,
    const float* __restrict__ bias, float* __restrict__ S)
{
    __shared__ __align__(16) float As[32][68];
    __shared__ __align__(16) float Bs[32][64];
    const int tid = threadIdx.x;
    const int tx = tid & 15, ty = tid >> 4;
    const int t0 = blockIdx.y * 64, e0 = blockIdx.x * 64;
    float acc[4][4] = {};
    for (int k0 = 0; k0 < HID; k0 += 32) {
#pragma unroll
        for (int j = 0; j < 8; ++j) {
            int i = tid + 256 * j;
            As[i & 31][i >> 5] = A[(size_t)(t0 + (i >> 5)) * HID + k0 + (i & 31)];
        }
#pragma unroll
        for (int j = 0; j < 8; ++j) {
            int i = tid + 256 * j;
            Bs[i >> 6][i & 63] = B[(size_t)(k0 + (i >> 6)) * EXPERTS + e0 + (i & 63)];
        }
        __syncthreads();
#pragma unroll
        for (int kk = 0; kk < 32; ++kk) {
            float4 a4 = *(const float4*)&As[kk][ty * 4];
            float4 b4 = *(const float4*)&Bs[kk][tx * 4];
            float aa[4] = {a4.x, a4.y, a4.z, a4.w};
            float bb[4] = {b4.x, b4.y, b4.z, b4.w};
#pragma unroll
            for (int i2 = 0; i2 < 4; ++i2)
#pragma unroll
                for (int j2 = 0; j2 < 4; ++j2)
                    acc[i2][j2] = fmaf(aa[i2], bb[j2], acc[i2][j2]);
        }
        __syncthreads();
    }
#pragma unroll
    for (int i2 = 0; i2 < 4; ++i2)
#pragma unroll
        for (int j2 = 0; j2 < 4; ++j2) {
            int t = t0 + ty * 4 + i2, e = e0 + tx * 4 + j2;
            S[(size_t)t * EXPERTS + e] = 1.0f / (1.0f + __expf(-acc[i2][j2])) + bias[e];
        }
}

__global__ __launch_bounds__(256) void route_topk(
    const float* __restrict__ S, float* __restrict__ out, int T)
{
    int t = blockIdx.x * blockDim.x + threadIdx.x;
    if (t >= T) return;
    const float4* s4 = (const float4*)(S + (size_t)t * EXPERTS);
    float gsum[8];
#pragma unroll
    for (int g = 0; g < 8; ++g) {
        float m1 = -1e30f, m2 = -1e30f;
#pragma unroll
        for (int q = 0; q < 8; ++q) {
            float4 v = s4[g * 8 + q];
            float vv[4] = {v.x, v.y, v.z, v.w};
#pragma unroll
            for (int u = 0; u < 4; ++u) {
                float x = vv[u];
                if (x > m1) { m2 = m1; m1 = x; }
                else if (x > m2) { m2 = x; }
            }
        }
        gsum[g] = m1 + m2;
    }
    unsigned selmask = 0;
#pragma unroll
    for (int r = 0; r < 4; ++r) {
        float best = -1e30f; int bi = 0;
#pragma unroll
        for (int g = 0; g < 8; ++g) {
            bool taken = (selmask >> g) & 1u;
            if (!taken && gsum[g] > best) { best = gsum[g]; bi = g; }
        }
        selmask |= 1u << bi;
    }
    float w[8];
#pragma unroll
    for (int k = 0; k < 8; ++k) w[k] = 0.0f;
    for (int g = 0; g < 8; ++g) {
        if (!((selmask >> g) & 1u)) continue;
#pragma unroll
        for (int q = 0; q < 8; ++q) {
            float4 v = s4[g * 8 + q];
            float vv[4] = {v.x, v.y, v.z, v.w};
#pragma unroll
            for (int u = 0; u < 4; ++u) {
                float x = vv[u];
                if (x > w[7]) {
#pragma unroll
                    for (int k = 0; k < 8; ++k) {
                        float hi = fmaxf(w[k], x);
                        x = fminf(w[k], x);
                        w[k] = hi;
                    }
                }
            }
        }
    }
    float d = 1e-20f;
#pragma unroll
    for (int k = 0; k < 8; ++k) d += w[k];
    float inv = SCALE / d;
    float4 o0 = {w[0]*inv, w[1]*inv, w[2]*inv, w[3]*inv};
    float4 o1 = {w[4]*inv, w[5]*inv, w[6]*inv, w[7]*inv};
    float4* o = (float4*)(out + (size_t)t * TOPK);
    o[0] = o0; o[1] = o1;
}

extern "C" void kernel_launch(void* const* d_in, const int* in_sizes, int n_in,
                              void* d_out, int out_size, void* d_ws, size_t ws_size,
                              hipStream_t stream) {
    const float* A    = (const float*)d_in[0];   // [T, HID]
    const float* B    = (const float*)d_in[1];   // [HID, EXPERTS]
    const float* bias = (const float*)d_in[2];   // [EXPERTS]
    float* out = (float*)d_out;

    const size_t OFF_S = (size_t)8  << 20;                     // B_pack: 7.34 MB at 0
    const size_t SZ_S  = (size_t)T_TOK * EXPERTS * 4;          // 8 MB
    const size_t OFF_P = (size_t)16 << 20;
    const size_t SZ_P  = (size_t)KSPLIT * T_TOK * EXPERTS * 4; // 64 MB

    if (ws_size >= OFF_P + SZ_P) {
        // primary path: k-split partials, no atomics
        uint32_t* Bp = (uint32_t*)d_ws;
        float* P = (float*)((char*)d_ws + OFF_P);
        pack_b<<<896, 256, 0, stream>>>(B, Bp);
        dim3 g(KSPLIT, T_TOK / BM);
        gemm_bf16split<false><<<g, 256, 0, stream>>>(A, Bp, P);
        route_wave<<<T_TOK / 4, 256, 0, stream>>>(P, KSPLIT, bias, out);
    } else if (ws_size >= OFF_S + SZ_S) {
        // atomic accumulation path
        uint32_t* Bp = (uint32_t*)d_ws;
        float* S = (float*)((char*)d_ws + OFF_S);
        hipMemsetAsync(S, 0, SZ_S, stream);
        pack_b<<<896, 256, 0, stream>>>(B, Bp);
        dim3 g(KSPLIT, T_TOK / BM);
        gemm_bf16split<true><<<g, 256, 0, stream>>>(A, Bp, S);
        route_wave<<<T_TOK / 4, 256, 0, stream>>>(S, 1, bias, out);
    } else {
        // legacy fp32 path
        float* scores = (float*)d_ws;
        dim3 grid1(EXPERTS / 64, T_TOK / 64);
        gemm_sigmoid_bias<<<grid1, 256, 0, stream>>>(A, B, bias, scores);
        route_topk<<<(T_TOK + 255) / 256, 256, 0, stream>>>(scores, out, T_TOK);
    }
}